// Round 6
// baseline (442.684 us; speedup 1.0000x reference)
//
#include <hip/hip_runtime.h>
#include <stdint.h>

// ---- problem constants ----
#define HEADS 8
#define KSZ   4
#define STRD  2
#define BB    8
#define LL    2048
#define CC    1024
#define N3    3072
#define NW    1023            // windows
#define M1    (BB*LL)         // 16384 rows of qkv GEMM
#define M2    (BB*NW*KSZ)     // 32736 rows of out GEMM
#define M2PAD 32768
#define GK    1024            // K of both GEMMs
#define NTT   16              // K-tiles per output tile (GK/64)

typedef __bf16 bf16;
typedef __bf16 bf16x8 __attribute__((ext_vector_type(8)));
typedef float  f32x4  __attribute__((ext_vector_type(4)));
typedef unsigned int  u32;
typedef unsigned short u16;

__device__ __forceinline__ float bflo(u32 u) { return __uint_as_float(u << 16); }
__device__ __forceinline__ float bfhi(u32 u) { return __uint_as_float(u & 0xffff0000u); }
__device__ __forceinline__ u16 f2bf(float f) { bf16 b = (bf16)f; return __builtin_bit_cast(u16, b); }

#define AS3(p) ((__attribute__((address_space(3))) void*)(p))
#define AS1(p) ((const __attribute__((address_space(1))) void*)(p))

// ---------------- cast x (f32 -> bf16), vectorized ----------------
__global__ __launch_bounds__(256) void cast_x_k(const float* __restrict__ in,
                                                bf16* __restrict__ out, int n4)
{
    int i = blockIdx.x * 256 + threadIdx.x;
    int stride = gridDim.x * 256;
    for (; i < n4; i += stride) {
        float4 f = reinterpret_cast<const float4*>(in)[i];
        ushort4 u;
        u.x = f2bf(f.x); u.y = f2bf(f.y); u.z = f2bf(f.z); u.w = f2bf(f.w);
        reinterpret_cast<ushort4*>(out)[i] = u;
    }
}

// ---------------- transpose + cast: src f32 [R][Ccol] -> dst bf16 [Ccol][R] ----------------
__global__ __launch_bounds__(256) void transpose_cast_k(const float* __restrict__ src,
                                                        bf16* __restrict__ dst,
                                                        int R, int Ccol)
{
    __shared__ float t[32][33];
    int tx = threadIdx.x & 31, ty = threadIdx.x >> 5;   // 32 x 8
    int c0 = blockIdx.x * 32, r0 = blockIdx.y * 32;
#pragma unroll
    for (int yy = 0; yy < 32; yy += 8)
        t[ty + yy][tx] = src[(size_t)(r0 + ty + yy) * Ccol + c0 + tx];
    __syncthreads();
#pragma unroll
    for (int yy = 0; yy < 32; yy += 8)
        dst[(size_t)(c0 + ty + yy) * R + r0 + tx] = (bf16)t[tx][ty + yy];
}

// ---------------- persistent 256x256 8-phase bf16 GEMM (T2+T3+T4+T5) ----------------
// Same schedule/ledger as round 5 (verified race-free): stage A(j+2)@P3,
// B(j+2)@P4 into buf[j&1]; vmcnt(8) steady at P4, vmcnt(0) at j=JT-2.
// This round: address strength-reduction only (NBN template, running stage
// pointers, ds_read bases + immediate offsets).
__device__ __forceinline__ void stage4(const char* p0, bf16* dst, int wid)
{
#pragma unroll
    for (int qd = 0; qd < 4; ++qd)
        __builtin_amdgcn_global_load_lds(AS1(p0 + (size_t)qd * 16384),
                                         AS3(dst + (wid * 4 + qd) * 512), 16, 0, 0);
}

#define VMW(VM)                                                           \
    if (VM == 8)      asm volatile("s_waitcnt vmcnt(8)" ::: "memory");    \
    else if (VM == 0) asm volatile("s_waitcnt vmcnt(0)" ::: "memory");

#define KT(BUF, SPA, SPB, DOSTG, VM)                                                   \
{                                                                                      \
    /* P1: ds aLo(8)+bLo(4); MFMA m0-3 x n0-1 */                                       \
    _Pragma("unroll") for (int m = 0; m < 4; ++m)                                      \
        _Pragma("unroll") for (int ks = 0; ks < 2; ++ks)                               \
            aLo[m][ks] = *(const bf16x8*)(rdA[ks] + BUF * 32768 + m * 2048);           \
    _Pragma("unroll") for (int n = 0; n < 2; ++n)                                      \
        _Pragma("unroll") for (int ks = 0; ks < 2; ++ks)                               \
            bLo[n][ks] = *(const bf16x8*)(rdB[ks] + BUF * 32768 + n * 2048);           \
    __builtin_amdgcn_s_setprio(1);                                                     \
    _Pragma("unroll") for (int m = 0; m < 4; ++m)                                      \
        _Pragma("unroll") for (int n = 0; n < 2; ++n)                                  \
            _Pragma("unroll") for (int ks = 0; ks < 2; ++ks)                           \
                acc[m][n] = __builtin_amdgcn_mfma_f32_16x16x32_bf16(aLo[m][ks], bLo[n][ks], acc[m][n], 0, 0, 0); \
    __builtin_amdgcn_s_setprio(0);                                                     \
    __builtin_amdgcn_s_barrier();                                                      \
    __builtin_amdgcn_sched_barrier(0);                                                 \
    /* P2: ds aHi(8); MFMA m4-7 x n0-1 */                                              \
    _Pragma("unroll") for (int m = 0; m < 4; ++m)                                      \
        _Pragma("unroll") for (int ks = 0; ks < 2; ++ks)                               \
            aHi[m][ks] = *(const bf16x8*)(rdA[ks] + BUF * 32768 + 8192 + m * 2048);    \
    __builtin_amdgcn_s_setprio(1);                                                     \
    _Pragma("unroll") for (int m = 0; m < 4; ++m)                                      \
        _Pragma("unroll") for (int n = 0; n < 2; ++n)                                  \
            _Pragma("unroll") for (int ks = 0; ks < 2; ++ks)                           \
                acc[4 + m][n] = __builtin_amdgcn_mfma_f32_16x16x32_bf16(aHi[m][ks], bLo[n][ks], acc[4 + m][n], 0, 0, 0); \
    __builtin_amdgcn_s_setprio(0);                                                     \
    __builtin_amdgcn_s_barrier();                                                      \
    __builtin_amdgcn_sched_barrier(0);                                                 \
    /* P3: ds bHi(4); stage A(j+2); MFMA m4-7 x n2-3 */                                \
    _Pragma("unroll") for (int n = 0; n < 2; ++n)                                      \
        _Pragma("unroll") for (int ks = 0; ks < 2; ++ks)                               \
            bHi[n][ks] = *(const bf16x8*)(rdB[ks] + BUF * 32768 + 4096 + n * 2048);    \
    if (DOSTG) stage4((SPA), sA[BUF], wid);                                            \
    __builtin_amdgcn_s_setprio(1);                                                     \
    _Pragma("unroll") for (int m = 0; m < 4; ++m)                                      \
        _Pragma("unroll") for (int n = 0; n < 2; ++n)                                  \
            _Pragma("unroll") for (int ks = 0; ks < 2; ++ks)                           \
                acc[4 + m][2 + n] = __builtin_amdgcn_mfma_f32_16x16x32_bf16(aHi[m][ks], bHi[n][ks], acc[4 + m][2 + n], 0, 0, 0); \
    __builtin_amdgcn_s_setprio(0);                                                     \
    __builtin_amdgcn_s_barrier();                                                      \
    __builtin_amdgcn_sched_barrier(0);                                                 \
    /* P4: stage B(j+2); MFMA m0-3 x n2-3; counted vmcnt */                            \
    if (DOSTG) stage4((SPB), sB[BUF], wid);                                            \
    __builtin_amdgcn_s_setprio(1);                                                     \
    _Pragma("unroll") for (int m = 0; m < 4; ++m)                                      \
        _Pragma("unroll") for (int n = 0; n < 2; ++n)                                  \
            _Pragma("unroll") for (int ks = 0; ks < 2; ++ks)                           \
                acc[m][2 + n] = __builtin_amdgcn_mfma_f32_16x16x32_bf16(aLo[m][ks], bHi[n][ks], acc[m][2 + n], 0, 0, 0); \
    __builtin_amdgcn_s_setprio(0);                                                     \
    VMW(VM)                                                                            \
    __builtin_amdgcn_s_barrier();                                                      \
    __builtin_amdgcn_sched_barrier(0);                                                 \
}

template <int HAS_BIAS, int T, int NBN>
__global__ __launch_bounds__(512, 1) void gemm8p_k(const bf16* __restrict__ A,
                                                   const bf16* __restrict__ Bt,
                                                   bf16* __restrict__ Cb,
                                                   const float* __restrict__ bias)
{
    __shared__ __attribute__((aligned(16))) bf16 sA[2][256 * 64];
    __shared__ __attribute__((aligned(16))) bf16 sB[2][256 * 64];
    const int Nn = NBN << 8;

    const int tid = threadIdx.x;
    const int l = tid & 63, wid = tid >> 6;
    const int wm = wid >> 2, wn = wid & 3;
    const int l15 = l & 15, l4 = l >> 4;
    const int xr = (l & 7) << 4;                      // read-side byte XOR (row&7 == l&7)
    const int kch = ((l & 7) ^ ((l >> 3) & 7)) * 8;   // write-side inverse-swizzled k offset

    // XCD-aware block swizzle (grid = 256, % 8 == 0, bijective)
    const int nwg = gridDim.x;
    const int wg = ((blockIdx.x & 7) * (nwg >> 3)) + (blockIdx.x >> 3);

    // ds_read base pointers: 2 per matrix (per k-slice); everything else is
    // compile-time byte offsets (m*2048, +8192 aHi, +4096 bHi, +32768 buf1)
    const int rA = wm * 128 + l15;
    const int rB = wn * 64 + l15;
    const char* rdA[2];
    const char* rdB[2];
#pragma unroll
    for (int ks = 0; ks < 2; ++ks) {
        rdA[ks] = (const char*)&sA[0][0] + rA * 128 + ((ks * 64 + l4 * 16) ^ xr);
        rdB[ks] = (const char*)&sB[0][0] + rB * 128 + ((ks * 64 + l4 * 16) ^ xr);
    }

    // per-thread staging byte offset (source side, inverse-swizzled)
    const size_t thrOff = ((size_t)(l >> 3) * GK + kch) * 2;

    f32x4 acc[8][4] = {};
    bf16x8 aLo[4][2], aHi[4][2], bLo[2][2], bHi[2][2];

    // prologue: tile ti0, K-tiles 0 -> buf0, 1 -> buf1
    const int ti0 = wg * T;
    {
        int m0p = (ti0 / NBN) << 8, n0p = (ti0 % NBN) << 8;
        const char* pA0 = (const char*)A + (size_t)(m0p + wid * 32) * GK * 2 + thrOff;
        const char* pB0 = (const char*)Bt + (size_t)(n0p + wid * 32) * GK * 2 + thrOff;
        stage4(pA0, sA[0], wid);
        stage4(pB0, sB[0], wid);
        stage4(pA0 + 128, sA[1], wid);
        stage4(pB0 + 128, sB[1], wid);
    }
    asm volatile("s_waitcnt vmcnt(8)" ::: "memory");   // K-tile 0 landed
    __builtin_amdgcn_s_barrier();
    __builtin_amdgcn_sched_barrier(0);

    // running stage pointers, positioned at (tile ti0, kt=2)
    const char* pA;
    const char* pB;
    {
        int m0p = (ti0 / NBN) << 8, n0p = (ti0 % NBN) << 8;
        pA = (const char*)A + (size_t)(m0p + wid * 32) * GK * 2 + thrOff + 256;
        pB = (const char*)Bt + (size_t)(n0p + wid * 32) * GK * 2 + thrOff + 256;
    }

    for (int t = 0; t < T; ++t) {
        const int ti = wg * T + t;
        const int m0 = (ti / NBN) << 8, n0 = (ti % NBN) << 8;

        // j' = 0..13: stage within tile t (kt = j'+2), running pointers
        for (int jj = 0; jj < 7; ++jj) {
            KT(0, pA, pB, true, 8); pA += 128; pB += 128;
            KT(1, pA, pB, true, 8); pA += 128; pB += 128;
        }
        // j' = 14,15: stage tile t+1 (kt 0,1), or drain at the last tile
        if (t + 1 < T) {
            const int ti2 = ti + 1;
            const int m0n = (ti2 / NBN) << 8, n0n = (ti2 % NBN) << 8;
            const char* pAn = (const char*)A + (size_t)(m0n + wid * 32) * GK * 2 + thrOff;
            const char* pBn = (const char*)Bt + (size_t)(n0n + wid * 32) * GK * 2 + thrOff;
            KT(0, pAn, pBn, true, 8);
            KT(1, pAn + 128, pBn + 128, true, 8);
            pA = pAn + 256; pB = pBn + 256;
        } else {
            KT(0, pA, pB, false, 0);    // j = JT-2: drain
            KT(1, pA, pB, false, 99);   // j = JT-1: nothing outstanding
        }

        // epilogue for tile (m0, n0): no LDS access
#pragma unroll
        for (int m = 0; m < 8; ++m) {
            int row = m0 + wm * 128 + m * 16 + l4 * 4;
#pragma unroll
            for (int n = 0; n < 4; ++n) {
                int col = n0 + wn * 64 + n * 16 + l15;
                float bv = HAS_BIAS ? bias[col] : 0.f;
#pragma unroll
                for (int r = 0; r < 4; ++r)
                    Cb[(size_t)(row + r) * Nn + col] = (bf16)(acc[m][n][r] + bv);
            }
        }
        if (t + 1 < T) {
#pragma unroll
            for (int m = 0; m < 8; ++m)
#pragma unroll
                for (int n = 0; n < 4; ++n)
#pragma unroll
                    for (int r = 0; r < 4; ++r)
                        acc[m][n][r] = 0.f;
        }
    }
}

// ---------------- windowed attention: 4 waves/block, 1 wave per (b, n, h) ----------------
// qkv bf16 [B*L][3072]; ob bf16 [(b*NW+n)*4+q][1024]
__global__ __launch_bounds__(256) void attn_k(const bf16* __restrict__ qkv,
                                              bf16* __restrict__ ob)
{
    int task = blockIdx.x * 4 + (threadIdx.x >> 6);
    int h = task & 7;
    int tmp = task >> 3;
    int n = tmp % NW;
    int b = tmp / NW;
    int l = threadIdx.x & 63;
    const size_t rowbase = ((size_t)b * LL + 2 * n) * N3;
    const int coff = h * 128 + 2 * l;    // this lane's 2 d-elements

    float q[KSZ][2], k[KSZ][2], v[KSZ][2];
#pragma unroll
    for (int i = 0; i < KSZ; ++i) {
        const bf16* rp = qkv + rowbase + (size_t)i * N3;
        u32 uq = *reinterpret_cast<const u32*>(rp + coff);
        u32 uk = *reinterpret_cast<const u32*>(rp + 1024 + coff);
        u32 uv = *reinterpret_cast<const u32*>(rp + 2048 + coff);
        q[i][0] = bflo(uq); q[i][1] = bfhi(uq);
        k[i][0] = bflo(uk); k[i][1] = bfhi(uk);
        v[i][0] = bflo(uv); v[i][1] = bfhi(uv);
    }

    float dots[KSZ][KSZ];
#pragma unroll
    for (int i = 0; i < KSZ; ++i)
#pragma unroll
        for (int j = 0; j < KSZ; ++j) {
            float p = q[i][0] * k[j][0] + q[i][1] * k[j][1];
#pragma unroll
            for (int off = 32; off >= 1; off >>= 1)
                p += __shfl_xor(p, off);
            dots[i][j] = p * 0.03125f;   // * C^-0.5
        }

#pragma unroll
    for (int i = 0; i < KSZ; ++i) {
        float m = fmaxf(fmaxf(dots[i][0], dots[i][1]), fmaxf(dots[i][2], dots[i][3]));
        float e[KSZ], s = 0.f;
#pragma unroll
        for (int j = 0; j < KSZ; ++j) { e[j] = __expf(dots[i][j] - m); s += e[j]; }
        float inv = 1.f / s;
        float o0 = 0.f, o1 = 0.f;
#pragma unroll
        for (int j = 0; j < KSZ; ++j) {
            float a = e[j] * inv;
            o0 += a * v[j][0];
            o1 += a * v[j][1];
        }
        size_t orow = (size_t)(b * NW + n) * KSZ + i;
        u32 pk = (u32)f2bf(o0) | ((u32)f2bf(o1) << 16);
        *reinterpret_cast<u32*>(ob + orow * CC + coff) = pk;
    }
}

// ---------------- gather: out[b][l][:] = sum of 1-2 contributing y rows ----------------
__global__ __launch_bounds__(256) void gather_k(const bf16* __restrict__ yb,
                                                float* __restrict__ out)
{
    size_t i = (size_t)blockIdx.x * 256 + threadIdx.x;   // over B*L*C/2 pairs
    size_t e0 = i * 2;
    int col = (int)(e0 & (CC - 1));
    size_t row = e0 >> 10;          // b*L + l
    int l = (int)(row & (LL - 1));
    int b = (int)(row >> 11);

    float s0 = 0.f, s1 = 0.f;
    int n1 = l >> 1, q1 = l & 1;
    if (n1 <= NW - 1) {
        size_t r = (size_t)(b * NW + n1) * KSZ + q1;
        u32 u = *reinterpret_cast<const u32*>(yb + r * CC + col);
        s0 += bflo(u); s1 += bfhi(u);
    }
    int n0v = n1 - 1, q0 = (l & 1) + 2;
    if (n0v >= 0) {
        size_t r = (size_t)(b * NW + n0v) * KSZ + q0;
        u32 u = *reinterpret_cast<const u32*>(yb + r * CC + col);
        s0 += bflo(u); s1 += bfhi(u);
    }
    float2 o; o.x = s0; o.y = s1;
    *reinterpret_cast<float2*>(out + e0) = o;
}

// ---------------- launch ----------------
extern "C" void kernel_launch(void* const* d_in, const int* in_sizes, int n_in,
                              void* d_out, int out_size, void* d_ws, size_t ws_size,
                              hipStream_t stream)
{
    const float* x     = (const float*)d_in[0];
    const float* w_qkv = (const float*)d_in[1];
    const float* w_out = (const float*)d_in[2];
    const float* b_out = (const float*)d_in[3];
    float* out = (float*)d_out;
    char* ws = (char*)d_ws;

    // ws layout (bytes):
    bf16* xb    = (bf16*)(ws);                  // 16384*1024*2  = 33,554,432
    bf16* wqkvT = (bf16*)(ws + 33554432);       //  3072*1024*2  =  6,291,456
    bf16* woutT = (bf16*)(ws + 39845888);       //  1024*1024*2  =  2,097,152
    bf16* qkvb  = (bf16*)(ws + 41943040);       // 16384*3072*2  = 100,663,296
    bf16* yb    = (bf16*)(ws + 41943040);       // aliases qkvb (dead after attn): 32768*1024*2
    bf16* ob    = (bf16*)(ws + 142606336);      // 32768*1024*2  = 67,108,864  (rows padded to 32768)
    // total: 209,715,200 bytes

    cast_x_k<<<2048, 256, 0, stream>>>(x, xb, M1 * CC / 4);
    transpose_cast_k<<<dim3(N3 / 32, CC / 32), 256, 0, stream>>>(w_qkv, wqkvT, CC, N3);
    transpose_cast_k<<<dim3(CC / 32, CC / 32), 256, 0, stream>>>(w_out, woutT, CC, CC);

    // GEMM1: 16384x3072x1024 = 768 tiles -> 256 persistent blocks x 3 tiles
    gemm8p_k<0, 3, 12><<<256, 512, 0, stream>>>(xb, wqkvT, qkvb, nullptr);

    attn_k<<<BB * NW * HEADS / 4, 256, 0, stream>>>(qkvb, ob);

    // GEMM2: 32768x1024x1024 = 512 tiles -> 256 persistent blocks x 2 tiles
    gemm8p_k<1, 2, 4><<<256, 512, 0, stream>>>(ob, woutT, yb, b_out);

    gather_k<<<(BB * LL * CC / 2) / 256, 256, 0, stream>>>(yb, out);
}

// Round 7
// 273.802 us; speedup vs baseline: 1.6168x; 1.6168x over previous
//
#include <hip/hip_runtime.h>
#include <stdint.h>

// ---- problem constants ----
#define HEADS 8
#define KSZ   4
#define STRD  2
#define BB    8
#define LL    2048
#define CC    1024
#define N3    3072
#define NW    1023            // windows
#define M1    (BB*LL)         // 16384 rows of qkv GEMM (and of z GEMM)
#define GK    1024            // K of both GEMMs
#define NTT   16              // K-tiles per output tile (GK/64)

typedef __bf16 bf16;
typedef __bf16 bf16x8 __attribute__((ext_vector_type(8)));
typedef float  f32x4  __attribute__((ext_vector_type(4)));
typedef unsigned int  u32;
typedef unsigned short u16;

__device__ __forceinline__ float bflo(u32 u) { return __uint_as_float(u << 16); }
__device__ __forceinline__ float bfhi(u32 u) { return __uint_as_float(u & 0xffff0000u); }
__device__ __forceinline__ u16 f2bf(float f) { bf16 b = (bf16)f; return __builtin_bit_cast(u16, b); }
__device__ __forceinline__ u32 pkadd(u32 a, u32 b) {
    float lo = bflo(a) + bflo(b), hi = bfhi(a) + bfhi(b);
    return (u32)f2bf(lo) | ((u32)f2bf(hi) << 16);
}

#define AS3(p) ((__attribute__((address_space(3))) void*)(p))
#define AS1(p) ((const __attribute__((address_space(1))) void*)(p))

// ---------------- cast x (f32 -> bf16), vectorized ----------------
__global__ __launch_bounds__(256) void cast_x_k(const float* __restrict__ in,
                                                bf16* __restrict__ out, int n4)
{
    int i = blockIdx.x * 256 + threadIdx.x;
    int stride = gridDim.x * 256;
    for (; i < n4; i += stride) {
        float4 f = reinterpret_cast<const float4*>(in)[i];
        ushort4 u;
        u.x = f2bf(f.x); u.y = f2bf(f.y); u.z = f2bf(f.z); u.w = f2bf(f.w);
        reinterpret_cast<ushort4*>(out)[i] = u;
    }
}

// ---------------- transpose + cast: src f32 [R][Ccol] -> dst bf16 [Ccol][R] ----------------
__global__ __launch_bounds__(256) void transpose_cast_k(const float* __restrict__ src,
                                                        bf16* __restrict__ dst,
                                                        int R, int Ccol)
{
    __shared__ float t[32][33];
    int tx = threadIdx.x & 31, ty = threadIdx.x >> 5;   // 32 x 8
    int c0 = blockIdx.x * 32, r0 = blockIdx.y * 32;
#pragma unroll
    for (int yy = 0; yy < 32; yy += 8)
        t[ty + yy][tx] = src[(size_t)(r0 + ty + yy) * Ccol + c0 + tx];
    __syncthreads();
#pragma unroll
    for (int yy = 0; yy < 32; yy += 8)
        dst[(size_t)(c0 + ty + yy) * R + r0 + tx] = (bf16)t[tx][ty + yy];
}

// ---------------- persistent 256x256 8-phase bf16 GEMM (T2+T3+T4+T5) ----------------
// ROUND-5 BODY (verified 110us / race-free): rolled j-loop, stage A(j+2)@P3,
// B(j+2)@P4 into buf[j&1]; vmcnt(8) steady at P4, vmcnt(0) at j=JT-2.
// Changes this round: NBN is a template param (div -> magic mul, codegen
// stays rolled/compact); OUT_MODE 0 = bf16 C no bias, 1 = f32 C direct to
// d_out with bias[col]*cnt(row) fused (cnt=1 at l in {0,1,2046,2047} else 2).
__device__ __forceinline__ void stage8(const bf16* __restrict__ G, bf16* dst,
                                       int baserow, int kt,
                                       int wid, int l, int kch)
{
#pragma unroll
    for (int qd = 0; qd < 4; ++qd) {
        int row = ((wid * 4 + qd) << 3) + (l >> 3);
        const bf16* src = G + (size_t)(baserow + row) * GK + kt * 64 + kch;
        __builtin_amdgcn_global_load_lds(AS1(src), AS3(dst + (wid * 4 + qd) * 512), 16, 0, 0);
    }
}

template <int OUT_MODE, int T, int NBN>
__global__ __launch_bounds__(512, 1) void gemm8p_k(const bf16* __restrict__ A,
                                                   const bf16* __restrict__ Bt,
                                                   void* __restrict__ Cout,
                                                   const float* __restrict__ bias)
{
    __shared__ __attribute__((aligned(16))) bf16 sA[2][256 * 64];
    __shared__ __attribute__((aligned(16))) bf16 sB[2][256 * 64];
    const int Nn = NBN << 8;

    const int tid = threadIdx.x;
    const int l = tid & 63, wid = tid >> 6;
    const int wm = wid >> 2, wn = wid & 3;
    const int l15 = l & 15, l4 = l >> 4;
    const int xr = (l & 7) << 4;                      // read-side byte XOR (row&7 == l&7)
    const int kch = ((l & 7) ^ ((l >> 3) & 7)) * 8;   // write-side inverse-swizzled k offset

    // XCD-aware block swizzle (grid = 256, % 8 == 0, bijective)
    const int nwg = gridDim.x;
    const int wg = ((blockIdx.x & 7) * (nwg >> 3)) + (blockIdx.x >> 3);
    const int JT = T * NTT;

    int ti = wg * T;                                  // current output tile
    int m0 = (ti / NBN) << 8, n0 = (ti % NBN) << 8;

    const int rA = wm * 128 + l15;
    const int rB = wn * 64 + l15;
    int offK[2];
#pragma unroll
    for (int ks = 0; ks < 2; ++ks)
        offK[ks] = ((ks * 64 + l4 * 16) ^ xr) >> 1;

    f32x4 acc[8][4] = {};
    bf16x8 aLo[4][2], aHi[4][2], bLo[2][2], bHi[2][2];

    // prologue: K-tile 0 -> buf0, K-tile 1 -> buf1 (tile ti)
    stage8(A, sA[0], m0, 0, wid, l, kch);
    stage8(Bt, sB[0], n0, 0, wid, l, kch);
    stage8(A, sA[1], m0, 1, wid, l, kch);
    stage8(Bt, sB[1], n0, 1, wid, l, kch);
    asm volatile("s_waitcnt vmcnt(8)" ::: "memory");   // K-tile 0 landed
    __builtin_amdgcn_s_barrier();
    __builtin_amdgcn_sched_barrier(0);

    for (int j = 0; j < JT; ++j) {
        const bf16* tA = sA[j & 1];
        const bf16* tB = sB[j & 1];
        bf16* wA = sA[j & 1];
        bf16* wB = sB[j & 1];

        // next-stage coordinates (tile of j+2)
        const int jn = j + 2;
        const bool doStage = jn < JT;
        int ktn = jn & (NTT - 1), m0n = 0, n0n = 0;
        if (doStage) {
            int tin = wg * T + (jn >> 4);              // NTT == 16
            m0n = (tin / NBN) << 8;
            n0n = (tin % NBN) << 8;
        }

        // ---- P1: ds aLo(8) + bLo(4); MFMA m0-3 x n0-1 ----
#pragma unroll
        for (int m = 0; m < 4; ++m)
#pragma unroll
            for (int ks = 0; ks < 2; ++ks)
                aLo[m][ks] = *reinterpret_cast<const bf16x8*>(&tA[(rA + m * 16) * 64 + offK[ks]]);
#pragma unroll
        for (int n = 0; n < 2; ++n)
#pragma unroll
            for (int ks = 0; ks < 2; ++ks)
                bLo[n][ks] = *reinterpret_cast<const bf16x8*>(&tB[(rB + n * 16) * 64 + offK[ks]]);
        __builtin_amdgcn_s_setprio(1);
#pragma unroll
        for (int m = 0; m < 4; ++m)
#pragma unroll
            for (int n = 0; n < 2; ++n)
#pragma unroll
                for (int ks = 0; ks < 2; ++ks)
                    acc[m][n] = __builtin_amdgcn_mfma_f32_16x16x32_bf16(aLo[m][ks], bLo[n][ks], acc[m][n], 0, 0, 0);
        __builtin_amdgcn_s_setprio(0);
        __builtin_amdgcn_s_barrier();
        __builtin_amdgcn_sched_barrier(0);

        // ---- P2: ds aHi(8); MFMA m4-7 x n0-1 ----  (A region fully read after this)
#pragma unroll
        for (int m = 0; m < 4; ++m)
#pragma unroll
            for (int ks = 0; ks < 2; ++ks)
                aHi[m][ks] = *reinterpret_cast<const bf16x8*>(&tA[(rA + 64 + m * 16) * 64 + offK[ks]]);
        __builtin_amdgcn_s_setprio(1);
#pragma unroll
        for (int m = 0; m < 4; ++m)
#pragma unroll
            for (int n = 0; n < 2; ++n)
#pragma unroll
                for (int ks = 0; ks < 2; ++ks)
                    acc[4 + m][n] = __builtin_amdgcn_mfma_f32_16x16x32_bf16(aHi[m][ks], bLo[n][ks], acc[4 + m][n], 0, 0, 0);
        __builtin_amdgcn_s_setprio(0);
        __builtin_amdgcn_s_barrier();
        __builtin_amdgcn_sched_barrier(0);

        // ---- P3: ds bHi(4); stage A(j+2) into freed A region; MFMA m4-7 x n2-3 ----
#pragma unroll
        for (int n = 0; n < 2; ++n)
#pragma unroll
            for (int ks = 0; ks < 2; ++ks)
                bHi[n][ks] = *reinterpret_cast<const bf16x8*>(&tB[(rB + 32 + n * 16) * 64 + offK[ks]]);
        if (doStage)
            stage8(A, wA, m0n, ktn, wid, l, kch);
        __builtin_amdgcn_s_setprio(1);
#pragma unroll
        for (int m = 0; m < 4; ++m)
#pragma unroll
            for (int n = 0; n < 2; ++n)
#pragma unroll
                for (int ks = 0; ks < 2; ++ks)
                    acc[4 + m][2 + n] = __builtin_amdgcn_mfma_f32_16x16x32_bf16(aHi[m][ks], bHi[n][ks], acc[4 + m][2 + n], 0, 0, 0);
        __builtin_amdgcn_s_setprio(0);
        __builtin_amdgcn_s_barrier();
        __builtin_amdgcn_sched_barrier(0);

        // ---- P4: stage B(j+2) into freed B region; MFMA m0-3 x n2-3; counted vmcnt ----
        if (doStage)
            stage8(Bt, wB, n0n, ktn, wid, l, kch);
        __builtin_amdgcn_s_setprio(1);
#pragma unroll
        for (int m = 0; m < 4; ++m)
#pragma unroll
            for (int n = 0; n < 2; ++n)
#pragma unroll
                for (int ks = 0; ks < 2; ++ks)
                    acc[m][2 + n] = __builtin_amdgcn_mfma_f32_16x16x32_bf16(aLo[m][ks], bHi[n][ks], acc[m][2 + n], 0, 0, 0);
        __builtin_amdgcn_s_setprio(0);
        if (j < JT - 2)
            asm volatile("s_waitcnt vmcnt(8)" ::: "memory");   // K-tile j+1 landed
        else if (j == JT - 2)
            asm volatile("s_waitcnt vmcnt(0)" ::: "memory");   // drain for last tile
        __builtin_amdgcn_s_barrier();
        __builtin_amdgcn_sched_barrier(0);

        // ---- output-tile boundary: epilogue (no LDS access), then reset ----
        if ((j & (NTT - 1)) == NTT - 1) {
            if (OUT_MODE == 0) {
                bf16* Cb = (bf16*)Cout;
#pragma unroll
                for (int m = 0; m < 8; ++m) {
                    int row = m0 + wm * 128 + m * 16 + l4 * 4;
#pragma unroll
                    for (int n = 0; n < 4; ++n) {
                        int col = n0 + wn * 64 + n * 16 + l15;
#pragma unroll
                        for (int r = 0; r < 4; ++r)
                            Cb[(size_t)(row + r) * Nn + col] = (bf16)acc[m][n][r];
                    }
                }
            } else {
                float* Cf = (float*)Cout;
#pragma unroll
                for (int m = 0; m < 8; ++m) {
                    int row = m0 + wm * 128 + m * 16 + l4 * 4;
#pragma unroll
                    for (int n = 0; n < 4; ++n) {
                        int col = n0 + wn * 64 + n * 16 + l15;
                        float bv = bias[col];
#pragma unroll
                        for (int r = 0; r < 4; ++r) {
                            int lrow = (row + r) & (LL - 1);
                            float cnt = (lrow < 2 || lrow > LL - 3) ? 1.f : 2.f;
                            Cf[(size_t)(row + r) * Nn + col] = acc[m][n][r] + bv * cnt;
                        }
                    }
                }
            }
            if (j + 1 < JT) {
#pragma unroll
                for (int m = 0; m < 8; ++m)
#pragma unroll
                    for (int n = 0; n < 4; ++n)
#pragma unroll
                        for (int r = 0; r < 4; ++r)
                            acc[m][n][r] = 0.f;
                ti += 1;
                m0 = (ti / NBN) << 8;
                n0 = (ti % NBN) << 8;
            }
        }
    }
}

// ---------------- windowed attention: 4 waves/block, 1 wave per (b, n, h) ----------------
// qkv bf16 [B*L][3072]; ob bf16 [(b*NW+n)*4+q][1024]
__global__ __launch_bounds__(256) void attn_k(const bf16* __restrict__ qkv,
                                              bf16* __restrict__ ob)
{
    int task = blockIdx.x * 4 + (threadIdx.x >> 6);
    int h = task & 7;
    int tmp = task >> 3;
    int n = tmp % NW;
    int b = tmp / NW;
    int l = threadIdx.x & 63;
    const size_t rowbase = ((size_t)b * LL + 2 * n) * N3;
    const int coff = h * 128 + 2 * l;    // this lane's 2 d-elements

    float q[KSZ][2], k[KSZ][2], v[KSZ][2];
#pragma unroll
    for (int i = 0; i < KSZ; ++i) {
        const bf16* rp = qkv + rowbase + (size_t)i * N3;
        u32 uq = *reinterpret_cast<const u32*>(rp + coff);
        u32 uk = *reinterpret_cast<const u32*>(rp + 1024 + coff);
        u32 uv = *reinterpret_cast<const u32*>(rp + 2048 + coff);
        q[i][0] = bflo(uq); q[i][1] = bfhi(uq);
        k[i][0] = bflo(uk); k[i][1] = bfhi(uk);
        v[i][0] = bflo(uv); v[i][1] = bfhi(uv);
    }

    float dots[KSZ][KSZ];
#pragma unroll
    for (int i = 0; i < KSZ; ++i)
#pragma unroll
        for (int j = 0; j < KSZ; ++j) {
            float p = q[i][0] * k[j][0] + q[i][1] * k[j][1];
#pragma unroll
            for (int off = 32; off >= 1; off >>= 1)
                p += __shfl_xor(p, off);
            dots[i][j] = p * 0.03125f;   // * C^-0.5
        }

#pragma unroll
    for (int i = 0; i < KSZ; ++i) {
        float m = fmaxf(fmaxf(dots[i][0], dots[i][1]), fmaxf(dots[i][2], dots[i][3]));
        float e[KSZ], s = 0.f;
#pragma unroll
        for (int j = 0; j < KSZ; ++j) { e[j] = __expf(dots[i][j] - m); s += e[j]; }
        float inv = 1.f / s;
        float o0 = 0.f, o1 = 0.f;
#pragma unroll
        for (int j = 0; j < KSZ; ++j) {
            float a = e[j] * inv;
            o0 += a * v[j][0];
            o1 += a * v[j][1];
        }
        size_t orow = (size_t)(b * NW + n) * KSZ + i;
        u32 pk = (u32)f2bf(o0) | ((u32)f2bf(o1) << 16);
        *reinterpret_cast<u32*>(ob + orow * CC + coff) = pk;
    }
}

// ---------------- presum: z[b*2048+l][:] = sum of the <=2 contributing ob rows ----------------
// out row l gets (n1=l>>1, q=l&1) if n1<=1022, plus (n1-1, q=(l&1)+2) if n1>=1.
__global__ __launch_bounds__(256) void presum_k(const bf16* __restrict__ ob,
                                                bf16* __restrict__ z)
{
    int i = blockIdx.x * 256 + threadIdx.x;   // over 16384*128 chunks of 8 bf16
    int c = (i & 127) * 8;
    int row = i >> 7;                          // b*2048 + l
    int l = row & (LL - 1);
    int b = row >> 11;
    const int n1 = l >> 1;

    uint4 r;
    if (l < 2) {
        r = *reinterpret_cast<const uint4*>(ob + ((size_t)(b * NW + n1) * KSZ + (l & 1)) * CC + c);
    } else if (n1 > NW - 1) {   // l >= 2046
        r = *reinterpret_cast<const uint4*>(ob + ((size_t)(b * NW + n1 - 1) * KSZ + (l & 1) + 2) * CC + c);
    } else {
        uint4 a = *reinterpret_cast<const uint4*>(ob + ((size_t)(b * NW + n1) * KSZ + (l & 1)) * CC + c);
        uint4 d = *reinterpret_cast<const uint4*>(ob + ((size_t)(b * NW + n1 - 1) * KSZ + (l & 1) + 2) * CC + c);
        r.x = pkadd(a.x, d.x); r.y = pkadd(a.y, d.y);
        r.z = pkadd(a.z, d.z); r.w = pkadd(a.w, d.w);
    }
    *reinterpret_cast<uint4*>(z + (size_t)row * CC + c) = r;
}

// ---------------- launch ----------------
extern "C" void kernel_launch(void* const* d_in, const int* in_sizes, int n_in,
                              void* d_out, int out_size, void* d_ws, size_t ws_size,
                              hipStream_t stream)
{
    const float* x     = (const float*)d_in[0];
    const float* w_qkv = (const float*)d_in[1];
    const float* w_out = (const float*)d_in[2];
    const float* b_out = (const float*)d_in[3];
    float* out = (float*)d_out;
    char* ws = (char*)d_ws;

    // ws layout (bytes):
    bf16* xb    = (bf16*)(ws);                  // 16384*1024*2  = 33,554,432
    bf16* wqkvT = (bf16*)(ws + 33554432);       //  3072*1024*2  =  6,291,456
    bf16* woutT = (bf16*)(ws + 39845888);       //  1024*1024*2  =  2,097,152
    bf16* qkvb  = (bf16*)(ws + 41943040);       // 16384*3072*2  = 100,663,296
    bf16* z     = (bf16*)(ws + 41943040);       // aliases qkvb (dead after attn): 16384*1024*2
    bf16* ob    = (bf16*)(ws + 142606336);      // 32736 rows * 1024 * 2 (padded region)
    // total: 209,715,200 bytes

    cast_x_k<<<2048, 256, 0, stream>>>(x, xb, M1 * CC / 4);
    transpose_cast_k<<<dim3(N3 / 32, CC / 32), 256, 0, stream>>>(w_qkv, wqkvT, CC, N3);
    transpose_cast_k<<<dim3(CC / 32, CC / 32), 256, 0, stream>>>(w_out, woutT, CC, CC);

    // GEMM1: 16384x3072x1024 = 768 tiles -> 256 persistent blocks x 3 tiles
    gemm8p_k<0, 3, 12><<<256, 512, 0, stream>>>(xb, wqkvT, qkvb, nullptr);

    attn_k<<<BB * NW * HEADS / 4, 256, 0, stream>>>(qkvb, ob);

    // presum contributing o rows: z[B*L][1024]
    presum_k<<<(M1 * 128) / 256, 256, 0, stream>>>(ob, z);

    // GEMM2: 16384x1024x1024 = 256 tiles -> 256 blocks x 1 tile, f32 out + bias*cnt
    gemm8p_k<1, 1, 4><<<256, 512, 0, stream>>>(z, woutT, out, b_out);
}

// Round 8
// 231.190 us; speedup vs baseline: 1.9148x; 1.1843x over previous
//
#include <hip/hip_runtime.h>
#include <stdint.h>

// ---- problem constants ----
#define HEADS 8
#define KSZ   4
#define STRD  2
#define BB    8
#define LL    2048
#define CC    1024
#define N3    3072
#define NW    1023            // windows
#define M1    (BB*LL)         // 16384 rows of qkv GEMM (and of z GEMM)
#define GK    1024            // K of both GEMMs
#define NTT   16              // K-tiles per output tile (GK/64)

typedef __bf16 bf16;
typedef __bf16 bf16x8 __attribute__((ext_vector_type(8)));
typedef float  f32x4  __attribute__((ext_vector_type(4)));
typedef unsigned int  u32;
typedef unsigned short u16;

__device__ __forceinline__ float bflo(u32 u) { return __uint_as_float(u << 16); }
__device__ __forceinline__ float bfhi(u32 u) { return __uint_as_float(u & 0xffff0000u); }
__device__ __forceinline__ u16 f2bf(float f) { bf16 b = (bf16)f; return __builtin_bit_cast(u16, b); }

#define AS3(p) ((__attribute__((address_space(3))) void*)(p))
#define AS1(p) ((const __attribute__((address_space(1))) void*)(p))

// ---------------- cast x (f32 -> bf16), vectorized ----------------
__global__ __launch_bounds__(256) void cast_x_k(const float* __restrict__ in,
                                                bf16* __restrict__ out, int n4)
{
    int i = blockIdx.x * 256 + threadIdx.x;
    int stride = gridDim.x * 256;
    for (; i < n4; i += stride) {
        float4 f = reinterpret_cast<const float4*>(in)[i];
        ushort4 u;
        u.x = f2bf(f.x); u.y = f2bf(f.y); u.z = f2bf(f.z); u.w = f2bf(f.w);
        reinterpret_cast<ushort4*>(out)[i] = u;
    }
}

// ---------------- transpose + cast: src f32 [R][Ccol] -> dst bf16 [Ccol][R] ----------------
__global__ __launch_bounds__(256) void transpose_cast_k(const float* __restrict__ src,
                                                        bf16* __restrict__ dst,
                                                        int R, int Ccol)
{
    __shared__ float t[32][33];
    int tx = threadIdx.x & 31, ty = threadIdx.x >> 5;   // 32 x 8
    int c0 = blockIdx.x * 32, r0 = blockIdx.y * 32;
#pragma unroll
    for (int yy = 0; yy < 32; yy += 8)
        t[ty + yy][tx] = src[(size_t)(r0 + ty + yy) * Ccol + c0 + tx];
    __syncthreads();
#pragma unroll
    for (int yy = 0; yy < 32; yy += 8)
        dst[(size_t)(c0 + ty + yy) * R + r0 + tx] = (bf16)t[tx][ty + yy];
}

// ---------------- persistent 256x256 8-phase bf16 GEMM (T2+T3+T4+T5) ----------------
// ROUND-5 BODY (verified 110us / race-free): rolled j-loop, stage A(j+2)@P3,
// B(j+2)@P4 into buf[j&1]; vmcnt(8) steady at P4, vmcnt(0) at j=JT-2.
// NBN template param (div -> magic mul). OUT_MODE 0 = bf16 C no bias,
// 1 = f32 C direct to d_out with bias[col]*cnt(row) fused.
__device__ __forceinline__ void stage8(const bf16* __restrict__ G, bf16* dst,
                                       int baserow, int kt,
                                       int wid, int l, int kch)
{
#pragma unroll
    for (int qd = 0; qd < 4; ++qd) {
        int row = ((wid * 4 + qd) << 3) + (l >> 3);
        const bf16* src = G + (size_t)(baserow + row) * GK + kt * 64 + kch;
        __builtin_amdgcn_global_load_lds(AS1(src), AS3(dst + (wid * 4 + qd) * 512), 16, 0, 0);
    }
}

template <int OUT_MODE, int T, int NBN>
__global__ __launch_bounds__(512, 1) void gemm8p_k(const bf16* __restrict__ A,
                                                   const bf16* __restrict__ Bt,
                                                   void* __restrict__ Cout,
                                                   const float* __restrict__ bias)
{
    __shared__ __attribute__((aligned(16))) bf16 sA[2][256 * 64];
    __shared__ __attribute__((aligned(16))) bf16 sB[2][256 * 64];
    const int Nn = NBN << 8;

    const int tid = threadIdx.x;
    const int l = tid & 63, wid = tid >> 6;
    const int wm = wid >> 2, wn = wid & 3;
    const int l15 = l & 15, l4 = l >> 4;
    const int xr = (l & 7) << 4;                      // read-side byte XOR (row&7 == l&7)
    const int kch = ((l & 7) ^ ((l >> 3) & 7)) * 8;   // write-side inverse-swizzled k offset

    // XCD-aware block swizzle (grid = 256, % 8 == 0, bijective)
    const int nwg = gridDim.x;
    const int wg = ((blockIdx.x & 7) * (nwg >> 3)) + (blockIdx.x >> 3);
    const int JT = T * NTT;

    int ti = wg * T;                                  // current output tile
    int m0 = (ti / NBN) << 8, n0 = (ti % NBN) << 8;

    const int rA = wm * 128 + l15;
    const int rB = wn * 64 + l15;
    int offK[2];
#pragma unroll
    for (int ks = 0; ks < 2; ++ks)
        offK[ks] = ((ks * 64 + l4 * 16) ^ xr) >> 1;

    f32x4 acc[8][4] = {};
    bf16x8 aLo[4][2], aHi[4][2], bLo[2][2], bHi[2][2];

    // prologue: K-tile 0 -> buf0, K-tile 1 -> buf1 (tile ti)
    stage8(A, sA[0], m0, 0, wid, l, kch);
    stage8(Bt, sB[0], n0, 0, wid, l, kch);
    stage8(A, sA[1], m0, 1, wid, l, kch);
    stage8(Bt, sB[1], n0, 1, wid, l, kch);
    asm volatile("s_waitcnt vmcnt(8)" ::: "memory");   // K-tile 0 landed
    __builtin_amdgcn_s_barrier();
    __builtin_amdgcn_sched_barrier(0);

    for (int j = 0; j < JT; ++j) {
        const bf16* tA = sA[j & 1];
        const bf16* tB = sB[j & 1];
        bf16* wA = sA[j & 1];
        bf16* wB = sB[j & 1];

        // next-stage coordinates (tile of j+2)
        const int jn = j + 2;
        const bool doStage = jn < JT;
        int ktn = jn & (NTT - 1), m0n = 0, n0n = 0;
        if (doStage) {
            int tin = wg * T + (jn >> 4);              // NTT == 16
            m0n = (tin / NBN) << 8;
            n0n = (tin % NBN) << 8;
        }

        // ---- P1: ds aLo(8) + bLo(4); MFMA m0-3 x n0-1 ----
#pragma unroll
        for (int m = 0; m < 4; ++m)
#pragma unroll
            for (int ks = 0; ks < 2; ++ks)
                aLo[m][ks] = *reinterpret_cast<const bf16x8*>(&tA[(rA + m * 16) * 64 + offK[ks]]);
#pragma unroll
        for (int n = 0; n < 2; ++n)
#pragma unroll
            for (int ks = 0; ks < 2; ++ks)
                bLo[n][ks] = *reinterpret_cast<const bf16x8*>(&tB[(rB + n * 16) * 64 + offK[ks]]);
        __builtin_amdgcn_s_setprio(1);
#pragma unroll
        for (int m = 0; m < 4; ++m)
#pragma unroll
            for (int n = 0; n < 2; ++n)
#pragma unroll
                for (int ks = 0; ks < 2; ++ks)
                    acc[m][n] = __builtin_amdgcn_mfma_f32_16x16x32_bf16(aLo[m][ks], bLo[n][ks], acc[m][n], 0, 0, 0);
        __builtin_amdgcn_s_setprio(0);
        __builtin_amdgcn_s_barrier();
        __builtin_amdgcn_sched_barrier(0);

        // ---- P2: ds aHi(8); MFMA m4-7 x n0-1 ----  (A region fully read after this)
#pragma unroll
        for (int m = 0; m < 4; ++m)
#pragma unroll
            for (int ks = 0; ks < 2; ++ks)
                aHi[m][ks] = *reinterpret_cast<const bf16x8*>(&tA[(rA + 64 + m * 16) * 64 + offK[ks]]);
        __builtin_amdgcn_s_setprio(1);
#pragma unroll
        for (int m = 0; m < 4; ++m)
#pragma unroll
            for (int n = 0; n < 2; ++n)
#pragma unroll
                for (int ks = 0; ks < 2; ++ks)
                    acc[4 + m][n] = __builtin_amdgcn_mfma_f32_16x16x32_bf16(aHi[m][ks], bLo[n][ks], acc[4 + m][n], 0, 0, 0);
        __builtin_amdgcn_s_setprio(0);
        __builtin_amdgcn_s_barrier();
        __builtin_amdgcn_sched_barrier(0);

        // ---- P3: ds bHi(4); stage A(j+2) into freed A region; MFMA m4-7 x n2-3 ----
#pragma unroll
        for (int n = 0; n < 2; ++n)
#pragma unroll
            for (int ks = 0; ks < 2; ++ks)
                bHi[n][ks] = *reinterpret_cast<const bf16x8*>(&tB[(rB + 32 + n * 16) * 64 + offK[ks]]);
        if (doStage)
            stage8(A, wA, m0n, ktn, wid, l, kch);
        __builtin_amdgcn_s_setprio(1);
#pragma unroll
        for (int m = 0; m < 4; ++m)
#pragma unroll
            for (int n = 0; n < 2; ++n)
#pragma unroll
                for (int ks = 0; ks < 2; ++ks)
                    acc[4 + m][2 + n] = __builtin_amdgcn_mfma_f32_16x16x32_bf16(aHi[m][ks], bHi[n][ks], acc[4 + m][2 + n], 0, 0, 0);
        __builtin_amdgcn_s_setprio(0);
        __builtin_amdgcn_s_barrier();
        __builtin_amdgcn_sched_barrier(0);

        // ---- P4: stage B(j+2) into freed B region; MFMA m0-3 x n2-3; counted vmcnt ----
        if (doStage)
            stage8(Bt, wB, n0n, ktn, wid, l, kch);
        __builtin_amdgcn_s_setprio(1);
#pragma unroll
        for (int m = 0; m < 4; ++m)
#pragma unroll
            for (int n = 0; n < 2; ++n)
#pragma unroll
                for (int ks = 0; ks < 2; ++ks)
                    acc[m][2 + n] = __builtin_amdgcn_mfma_f32_16x16x32_bf16(aLo[m][ks], bHi[n][ks], acc[m][2 + n], 0, 0, 0);
        __builtin_amdgcn_s_setprio(0);
        if (j < JT - 2)
            asm volatile("s_waitcnt vmcnt(8)" ::: "memory");   // K-tile j+1 landed
        else if (j == JT - 2)
            asm volatile("s_waitcnt vmcnt(0)" ::: "memory");   // drain for last tile
        __builtin_amdgcn_s_barrier();
        __builtin_amdgcn_sched_barrier(0);

        // ---- output-tile boundary: epilogue (no LDS access), then reset ----
        if ((j & (NTT - 1)) == NTT - 1) {
            if (OUT_MODE == 0) {
                bf16* Cb = (bf16*)Cout;
#pragma unroll
                for (int m = 0; m < 8; ++m) {
                    int row = m0 + wm * 128 + m * 16 + l4 * 4;
#pragma unroll
                    for (int n = 0; n < 4; ++n) {
                        int col = n0 + wn * 64 + n * 16 + l15;
#pragma unroll
                        for (int r = 0; r < 4; ++r)
                            Cb[(size_t)(row + r) * Nn + col] = (bf16)acc[m][n][r];
                    }
                }
            } else {
                float* Cf = (float*)Cout;
#pragma unroll
                for (int m = 0; m < 8; ++m) {
                    int row = m0 + wm * 128 + m * 16 + l4 * 4;
#pragma unroll
                    for (int n = 0; n < 4; ++n) {
                        int col = n0 + wn * 64 + n * 16 + l15;
                        float bv = bias[col];
#pragma unroll
                        for (int r = 0; r < 4; ++r) {
                            int lrow = (row + r) & (LL - 1);
                            float cnt = (lrow < 2 || lrow > LL - 3) ? 1.f : 2.f;
                            Cf[(size_t)(row + r) * Nn + col] = acc[m][n][r] + bv * cnt;
                        }
                    }
                }
            }
            if (j + 1 < JT) {
#pragma unroll
                for (int m = 0; m < 8; ++m)
#pragma unroll
                    for (int n = 0; n < 4; ++n)
#pragma unroll
                        for (int r = 0; r < 4; ++r)
                            acc[m][n][r] = 0.f;
                ti += 1;
                m0 = (ti / NBN) << 8;
                n0 = (ti % NBN) << 8;
            }
        }
    }
}

// ---------------- fused windowed attention + presum: 4 waves/block ----------------
// One wave per (b, n1, h), n1 in [0,1024): produces z rows 2*n1 and 2*n1+1
// (the h-slice of each). z row l = o(window n1, slot l&1) + o(window n1-1,
// slot (l&1)+2); BOTH slots map to global q-row l, so q loads are shared.
// K/V rows needed: 2*n1-2 .. 2*n1+3 (6 rows, union of both windows).
// Unique dots per q-row: 6 (window A uses k[2..5], window B uses k[0..3]).
__global__ __launch_bounds__(256) void attnz_k(const bf16* __restrict__ qkv,
                                               bf16* __restrict__ z)
{
    int task = blockIdx.x * 4 + (threadIdx.x >> 6);   // (b, n1, h)
    int h = task & 7;
    int tmp = task >> 3;                              // b*1024 + n1
    int n1 = tmp & 1023;
    int b = tmp >> 10;
    int l = threadIdx.x & 63;
    const int coff = h * 128 + 2 * l;                 // this lane's 2 d-elements
    const int baserow = b * LL + 2 * n1;              // global row of q/z base
    const bool hasA = (n1 <= NW - 1);                 // window n1 exists
    const bool hasB = (n1 >= 1);                      // window n1-1 exists

    float q[2][2], k[6][2], v[6][2];
#pragma unroll
    for (int i = 0; i < 2; ++i) {
        const bf16* rp = qkv + (size_t)(baserow + i) * N3;
        u32 uq = *reinterpret_cast<const u32*>(rp + coff);
        q[i][0] = bflo(uq); q[i][1] = bfhi(uq);
    }
#pragma unroll
    for (int j = 0; j < 6; ++j) {
        int r = 2 * n1 - 2 + j;
        r = r < 0 ? 0 : (r > LL - 1 ? LL - 1 : r);    // clamp; clamped rows unused
        const bf16* rp = qkv + (size_t)(b * LL + r) * N3;
        u32 uk = *reinterpret_cast<const u32*>(rp + 1024 + coff);
        u32 uv = *reinterpret_cast<const u32*>(rp + 2048 + coff);
        k[j][0] = bflo(uk); k[j][1] = bfhi(uk);
        v[j][0] = bflo(uv); v[j][1] = bfhi(uv);
    }

    float dots[2][6];
#pragma unroll
    for (int i = 0; i < 2; ++i)
#pragma unroll
        for (int j = 0; j < 6; ++j) {
            float p = q[i][0] * k[j][0] + q[i][1] * k[j][1];
#pragma unroll
            for (int off = 32; off >= 1; off >>= 1)
                p += __shfl_xor(p, off);
            dots[i][j] = p * 0.03125f;   // * C^-0.5
        }

#pragma unroll
    for (int i = 0; i < 2; ++i) {
        float o0 = 0.f, o1 = 0.f;
        if (hasA) {    // window n1, k/v slots 2..5
            float m = fmaxf(fmaxf(dots[i][2], dots[i][3]), fmaxf(dots[i][4], dots[i][5]));
            float e[4], s = 0.f;
#pragma unroll
            for (int j = 0; j < 4; ++j) { e[j] = __expf(dots[i][2 + j] - m); s += e[j]; }
            float inv = 1.f / s;
#pragma unroll
            for (int j = 0; j < 4; ++j) {
                float a = e[j] * inv;
                o0 += a * v[2 + j][0];
                o1 += a * v[2 + j][1];
            }
        }
        if (hasB) {    // window n1-1, k/v slots 0..3
            float m = fmaxf(fmaxf(dots[i][0], dots[i][1]), fmaxf(dots[i][2], dots[i][3]));
            float e[4], s = 0.f;
#pragma unroll
            for (int j = 0; j < 4; ++j) { e[j] = __expf(dots[i][j] - m); s += e[j]; }
            float inv = 1.f / s;
#pragma unroll
            for (int j = 0; j < 4; ++j) {
                float a = e[j] * inv;
                o0 += a * v[j][0];
                o1 += a * v[j][1];
            }
        }
        u32 pk = (u32)f2bf(o0) | ((u32)f2bf(o1) << 16);
        *reinterpret_cast<u32*>(z + (size_t)(baserow + i) * CC + coff) = pk;
    }
}

// ---------------- launch ----------------
extern "C" void kernel_launch(void* const* d_in, const int* in_sizes, int n_in,
                              void* d_out, int out_size, void* d_ws, size_t ws_size,
                              hipStream_t stream)
{
    const float* x     = (const float*)d_in[0];
    const float* w_qkv = (const float*)d_in[1];
    const float* w_out = (const float*)d_in[2];
    const float* b_out = (const float*)d_in[3];
    float* out = (float*)d_out;
    char* ws = (char*)d_ws;

    // ws layout (bytes):
    bf16* xb    = (bf16*)(ws);                  // 16384*1024*2  = 33,554,432
    bf16* wqkvT = (bf16*)(ws + 33554432);       //  3072*1024*2  =  6,291,456
    bf16* woutT = (bf16*)(ws + 39845888);       //  1024*1024*2  =  2,097,152
    bf16* qkvb  = (bf16*)(ws + 41943040);       // 16384*3072*2  = 100,663,296 (ends 142,606,336)
    bf16* z     = (bf16*)(ws + 142606336);      // 16384*1024*2  = 33,554,432 (no aliasing with qkvb)
    // total: 176,160,768 bytes

    cast_x_k<<<2048, 256, 0, stream>>>(x, xb, M1 * CC / 4);
    transpose_cast_k<<<dim3(N3 / 32, CC / 32), 256, 0, stream>>>(w_qkv, wqkvT, CC, N3);
    transpose_cast_k<<<dim3(CC / 32, CC / 32), 256, 0, stream>>>(w_out, woutT, CC, CC);

    // GEMM1: 16384x3072x1024 = 768 tiles -> 256 persistent blocks x 3 tiles
    gemm8p_k<0, 3, 12><<<256, 512, 0, stream>>>(xb, wqkvT, qkvb, nullptr);

    // fused attention + presum: tasks = B*1024*H = 65536, 4 waves/block
    attnz_k<<<BB * 1024 * HEADS / 4, 256, 0, stream>>>(qkvb, z);

    // GEMM2: 16384x1024x1024 = 256 tiles -> 256 blocks x 1 tile, f32 out + bias*cnt
    gemm8p_k<1, 1, 4><<<256, 512, 0, stream>>>(z, woutT, out, b_out);
}